// Round 6
// baseline (278.948 us; speedup 1.0000x reference)
//
#include <hip/hip_runtime.h>

#define ALPHA 0.2f
#define LDA 136   // LDS row stride in shorts (272 B = 17*16: aligned, conflict-balanced)

typedef short bf16x8 __attribute__((ext_vector_type(8)));
typedef float f32x4  __attribute__((ext_vector_type(4)));

static __device__ __forceinline__ float bf2f(unsigned short u) {
    union { unsigned int i; float f; } v; v.i = ((unsigned int)u) << 16; return v.f;
}
static __device__ __forceinline__ unsigned short f2bf(float f) {
    union { float f; unsigned int i; } v; v.f = f;
    unsigned int x = v.i;
    return (unsigned short)((x + 0x7fffu + ((x >> 16) & 1u)) >> 16);  // RNE
}

// One-time: wT[c][k] = bf16(w[k][c]) for w1 (block 0) and w2 (block 1).
__global__ __launch_bounds__(256)
void prep_wT_kernel(const float* __restrict__ w1, const float* __restrict__ w2,
                    unsigned short* __restrict__ wT1, unsigned short* __restrict__ wT2)
{
    __shared__ unsigned short wL[128 * 130];   // +2 pad: conflict-free transpose
    const float* w = blockIdx.x ? w2 : w1;
    unsigned short* wT = blockIdx.x ? wT2 : wT1;
    const int tid = threadIdx.x;

    for (int i = 0; i < 16; i++) {             // 4096 float4 units
        int e = tid + i * 256;
        int k = e >> 5, c0 = (e & 31) * 4;
        float4 v = *(const float4*)&w[k * 128 + c0];
        wL[(c0 + 0) * 130 + k] = f2bf(v.x);
        wL[(c0 + 1) * 130 + k] = f2bf(v.y);
        wL[(c0 + 2) * 130 + k] = f2bf(v.z);
        wL[(c0 + 3) * 130 + k] = f2bf(v.w);
    }
    __syncthreads();
    for (int i = 0; i < 8; i++) {              // 2048 ushort8 units
        int e = tid + i * 256;
        int c = e >> 4, k0 = (e & 15) * 8;
        ushort4 a, b;
        a.x = wL[c * 130 + k0 + 0]; a.y = wL[c * 130 + k0 + 1];
        a.z = wL[c * 130 + k0 + 2]; a.w = wL[c * 130 + k0 + 3];
        b.x = wL[c * 130 + k0 + 4]; b.y = wL[c * 130 + k0 + 5];
        b.z = wL[c * 130 + k0 + 6]; b.w = wL[c * 130 + k0 + 7];
        *(ushort4*)&wT[c * 128 + k0]     = a;
        *(ushort4*)&wT[c * 128 + k0 + 4] = b;
    }
}

// MFMA GEMM + fused score dots (unchanged from round 5).
template <bool SRC_BF>
__global__ __launch_bounds__(256)
void gemm_score_mfma(const void* __restrict__ srcv,
                     const unsigned short* __restrict__ wT,   // [c][k] bf16
                     const float* __restrict__ a_in,
                     const float* __restrict__ a_out,
                     unsigned short* __restrict__ hid,
                     float* __restrict__ s_in,
                     float* __restrict__ s_out,
                     int n)
{
    __shared__ short As[64 * LDA];
    __shared__ short Bs[128 * LDA];
    __shared__ float aS[2][128];

    const int tid = threadIdx.x;
    const int rbase = blockIdx.x * 64;

    if (tid < 128) { aS[0][tid] = a_in[tid]; aS[1][tid] = a_out[tid]; }

    if (SRC_BF) {
        const unsigned short* src = (const unsigned short*)srcv;
        #pragma unroll
        for (int i = 0; i < 8; i++) {
            int e = tid + i * 256;
            int r = e >> 5, c4 = (e & 31) * 4;
            int gr = rbase + r;
            ushort4 v;
            if (gr < n) v = *(const ushort4*)&src[(size_t)gr * 128 + c4];
            else { v.x = v.y = v.z = v.w = 0; }
            *(ushort4*)&As[r * LDA + c4] = v;
        }
    } else {
        const float* src = (const float*)srcv;
        #pragma unroll
        for (int i = 0; i < 8; i++) {
            int e = tid + i * 256;
            int r = e >> 5, c4 = (e & 31) * 4;
            int gr = rbase + r;
            ushort4 u;
            if (gr < n) {
                float4 v = *(const float4*)&src[(size_t)gr * 128 + c4];
                u.x = f2bf(v.x); u.y = f2bf(v.y); u.z = f2bf(v.z); u.w = f2bf(v.w);
            } else { u.x = u.y = u.z = u.w = 0; }
            *(ushort4*)&As[r * LDA + c4] = u;
        }
    }
    #pragma unroll
    for (int i = 0; i < 8; i++) {
        int e = tid + i * 256;
        int nr = e >> 4, j = (e & 15) * 8;
        int4 v = *(const int4*)&wT[nr * 128 + j];
        *(int4*)&Bs[nr * LDA + j] = v;
    }
    __syncthreads();

    const int lane = tid & 63;
    const int wv = tid >> 6;
    const int m = lane & 15;
    const int q = lane >> 4;

    f32x4 acc[8];
    #pragma unroll
    for (int t = 0; t < 8; t++) acc[t] = (f32x4){0.f, 0.f, 0.f, 0.f};

    const short* Abase = &As[(wv * 16 + m) * LDA + q * 8];
    const short* Bbase = &Bs[m * LDA + q * 8];

    #pragma unroll
    for (int ks = 0; ks < 4; ks++) {
        bf16x8 aF = *(const bf16x8*)(Abase + ks * 32);
        #pragma unroll
        for (int t = 0; t < 8; t++) {
            bf16x8 bF = *(const bf16x8*)(Bbase + t * 16 * LDA + ks * 32);
            acc[t] = __builtin_amdgcn_mfma_f32_16x16x32_bf16(aF, bF, acc[t], 0, 0, 0);
        }
    }

    float pin[4] = {0.f, 0.f, 0.f, 0.f}, pout[4] = {0.f, 0.f, 0.f, 0.f};
    #pragma unroll
    for (int t = 0; t < 8; t++) {
        float ai = aS[0][t * 16 + m];
        float ao = aS[1][t * 16 + m];
        #pragma unroll
        for (int r = 0; r < 4; r++) {
            pin[r]  += acc[t][r] * ai;
            pout[r] += acc[t][r] * ao;
        }
    }
    #pragma unroll
    for (int msk = 8; msk >= 1; msk >>= 1) {
        #pragma unroll
        for (int r = 0; r < 4; r++) {
            pin[r]  += __shfl_xor(pin[r],  msk);
            pout[r] += __shfl_xor(pout[r], msk);
        }
    }
    if (m == 0) {
        #pragma unroll
        for (int r = 0; r < 4; r++) {
            int g = rbase + wv * 16 + q * 4 + r;
            if (g < n) { s_in[g] = pin[r]; s_out[g] = pout[r]; }
        }
    }

    #pragma unroll
    for (int t = 0; t < 8; t++)
        #pragma unroll
        for (int r = 0; r < 4; r++)
            As[(wv * 16 + q * 4 + r) * LDA + t * 16 + m] = (short)f2bf(acc[t][r]);
    __syncthreads();
    #pragma unroll
    for (int i = 0; i < 4; i++) {
        int e = tid + i * 256;
        int r = e >> 4, j = (e & 15) * 8;
        int gr = rbase + r;
        if (gr < n) {
            int4 v = *(const int4*)&As[r * LDA + j];
            *(int4*)&hid[(size_t)gr * 128 + j] = v;
        }
    }
}

// One wave per node, ZERO cross-lane ops: dst/adj/softmax are wave-uniform,
// so every lane redundantly computes the 16-way softmax in registers from
// broadcast loads; per-lane registers then drive the gather loop directly.
// out = relu( (1/sum_p) * sum_k (adj_k * p_k) * hid[dk_k] + b )
template <bool FINAL>
__global__ __launch_bounds__(256)
void gat_aggregate_kernel(const unsigned short* __restrict__ hid,
                          const float* __restrict__ s_in,
                          const float* __restrict__ s_out,
                          const int* __restrict__ dst,
                          const float* __restrict__ adj,
                          const float* __restrict__ bias,
                          void* __restrict__ outv,
                          int n)
{
    const int lane = threadIdx.x & 63;
    const int node = (blockIdx.x * 256 + threadIdx.x) >> 6;
    if (node >= n) return;

    // wave-uniform broadcast loads: 16 neighbor ids + 16 adj values
    int dk[16];
    float av[16];
    #pragma unroll
    for (int j = 0; j < 4; j++) {
        int4   dv = *(const int4*)&dst[node * 16 + j * 4];
        float4 av4 = *(const float4*)&adj[node * 16 + j * 4];
        dk[j * 4 + 0] = dv.x; dk[j * 4 + 1] = dv.y;
        dk[j * 4 + 2] = dv.z; dk[j * 4 + 3] = dv.w;
        av[j * 4 + 0] = av4.x; av[j * 4 + 1] = av4.y;
        av[j * 4 + 2] = av4.z; av[j * 4 + 3] = av4.w;
    }
    // scores (wave-uniform broadcast loads of s_out[dk])
    float e[16];
    const float si = s_in[node];
    #pragma unroll
    for (int k = 0; k < 16; k++) {
        float t = si + s_out[dk[k]];
        e[k] = (t > 0.f) ? t : ALPHA * t;          // LeakyReLU(0.2)
    }
    float mx = e[0];
    #pragma unroll
    for (int k = 1; k < 16; k++) mx = fmaxf(mx, e[k]);
    float sum = 0.f;
    #pragma unroll
    for (int k = 0; k < 16; k++) {
        float p = __expf(e[k] - mx);
        sum += p;
        e[k] = av[k] * p;                          // adj * unnormalized softmax
    }
    const float inv = __frcp_rn(sum);

    // gather: lane owns cols 2*lane, 2*lane+1; 16 independent 256B row reads
    const int c = lane * 2;
    float accx = 0.f, accy = 0.f;
    #pragma unroll
    for (int k = 0; k < 16; k++) {
        ushort2 hq = *(const ushort2*)&hid[(size_t)dk[k] * 128 + c];
        accx += e[k] * bf2f(hq.x);
        accy += e[k] * bf2f(hq.y);
    }
    float ox = fmaxf(accx * inv + bias[c],     0.f);
    float oy = fmaxf(accy * inv + bias[c + 1], 0.f);

    const size_t oidx = (size_t)node * 128 + c;
    if (FINAL) {
        *(float2*)&((float*)outv)[oidx] = make_float2(ox, oy);
    } else {
        ushort2 ov; ov.x = f2bf(ox); ov.y = f2bf(oy);
        *(ushort2*)&((unsigned short*)outv)[oidx] = ov;
    }
}

extern "C" void kernel_launch(void* const* d_in, const int* in_sizes, int n_in,
                              void* d_out, int out_size, void* d_ws, size_t ws_size,
                              hipStream_t stream)
{
    const float* x      = (const float*)d_in[0];
    const int*   dst    = (const int*)d_in[1];
    const float* adj    = (const float*)d_in[2];
    const float* w1     = (const float*)d_in[3];
    const float* a_in1  = (const float*)d_in[4];
    const float* a_out1 = (const float*)d_in[5];
    const float* b1     = (const float*)d_in[6];
    const float* w2     = (const float*)d_in[7];
    const float* a_in2  = (const float*)d_in[8];
    const float* a_out2 = (const float*)d_in[9];
    const float* b2     = (const float*)d_in[10];

    const int N = in_sizes[0] / 128;               // 100000

    // ws: hid bf16 (25.6MB) | s_in f32 | s_out f32 | wT1 bf16 | wT2 bf16
    unsigned short* hid   = (unsigned short*)d_ws;
    float*          s_in  = (float*)(hid + (size_t)N * 128);
    float*          s_out = s_in + N;
    unsigned short* wT1   = (unsigned short*)(s_out + N);
    unsigned short* wT2   = wT1 + 128 * 128;
    // layer-1 activation h1 (bf16) lives in the upper half of the fp32 d_out
    unsigned short* h1    = (unsigned short*)d_out + out_size;

    dim3 blk(256);
    dim3 ggrid((N + 63) / 64);                     // 1563
    dim3 agrid((N + 3) / 4);                       // 25000 (1 node per wave)

    prep_wT_kernel<<<2, blk, 0, stream>>>(w1, w2, wT1, wT2);

    gemm_score_mfma<false><<<ggrid, blk, 0, stream>>>(x,  wT1, a_in1, a_out1,
                                                      hid, s_in, s_out, N);
    gat_aggregate_kernel<false><<<agrid, blk, 0, stream>>>(hid, s_in, s_out, dst,
                                                           adj, b1, h1, N);
    gemm_score_mfma<true><<<ggrid, blk, 0, stream>>>(h1, wT2, a_in2, a_out2,
                                                     hid, s_in, s_out, N);
    gat_aggregate_kernel<true><<<agrid, blk, 0, stream>>>(hid, s_in, s_out, dst,
                                                          adj, b2, d_out, N);
}